// Round 5
// baseline (1166.224 us; speedup 1.0000x reference)
//
#include <hip/hip_runtime.h>
#include <hip/hip_bf16.h>

#define NN 50000
#define NE 1600000
#define NR 8
#define D 128
#define DOUT 64
#define NCB ((NN + 63) / 64)          // 782 coarse buckets (dst>>6)
#define GRIDM ((NN + 63) / 64)        // 782 M-tiles for MFMA GEMM

typedef __attribute__((ext_vector_type(8))) __bf16 bf16x8;
typedef __attribute__((ext_vector_type(4))) float f32x4;

__device__ __forceinline__ float bflo(unsigned u) { return __uint_as_float(u << 16); }
__device__ __forceinline__ float bfhi(unsigned u) { return __uint_as_float(u & 0xffff0000u); }
__device__ __forceinline__ unsigned f2bf_rne(float x) {
    unsigned u = __float_as_uint(x);
    return (u + 0x7fffu + ((u >> 16) & 1u)) >> 16;
}
__device__ __forceinline__ unsigned pack2(float a, float b) {
    return f2bf_rne(a) | (f2bf_rne(b) << 16);
}

// ---------------- CSR build: coarse hist -> scan -> bucket scatter -> build ----

__global__ __launch_bounds__(1024)
void k_chist(const int* __restrict__ ei, int* __restrict__ ccnt) {
    __shared__ int h[NCB];
    for (int i = threadIdx.x; i < NCB; i += 1024) h[i] = 0;
    __syncthreads();
    for (int e = blockIdx.x * 1024 + threadIdx.x; e < NE; e += gridDim.x * 1024)
        atomicAdd(&h[ei[NE + e] >> 6], 1);
    __syncthreads();
    for (int i = threadIdx.x; i < NCB; i += 1024)
        if (h[i]) atomicAdd(&ccnt[i], h[i]);
}

__global__ __launch_bounds__(1024)
void k_cscan(const int* __restrict__ ccnt, int* __restrict__ cbase,
             int* __restrict__ ccur, int* __restrict__ off) {
    __shared__ int s[1024];
    int t = threadIdx.x;
    int v = (t < NCB) ? ccnt[t] : 0;
    s[t] = v;
    __syncthreads();
    for (int o = 1; o < 1024; o <<= 1) {
        int x = (t >= o) ? s[t - o] : 0;
        __syncthreads();
        s[t] += x;
        __syncthreads();
    }
    if (t < NCB) { cbase[t] = s[t] - v; ccur[t] = s[t] - v; }
    if (t == 0) { cbase[NCB] = NE; off[NN] = NE; }
}

// pack: dstlo(6) << 19 | rel(3) << 16 | src(16)
__global__ __launch_bounds__(1024)
void k_cscatter(const int* __restrict__ ei, const int* __restrict__ et,
                int* __restrict__ ccur, int* __restrict__ bck) {
    for (int e = blockIdx.x * 1024 + threadIdx.x; e < NE; e += gridDim.x * 1024) {
        int dst = ei[NE + e];
        int pk = ((dst & 63) << 19) | (et[e] << 16) | ei[e];
        int p = atomicAdd(&ccur[dst >> 6], 1);
        bck[p] = pk;
    }
}

// per coarse bucket: per-dst counts (LDS), scan, write off/invdeg, local scatter
__global__ __launch_bounds__(256)
void k_build(const int* __restrict__ bck, const int* __restrict__ cbase,
             int* __restrict__ off, float* __restrict__ invdeg,
             int* __restrict__ esrcF) {
    __shared__ int cnt[64];
    __shared__ int cur[64];
    __shared__ int sb[2];
    const int b = blockIdx.x;
    const int tid = threadIdx.x;
    if (tid < 64) cnt[tid] = 0;
    if (tid == 0) { sb[0] = cbase[b]; sb[1] = cbase[b + 1]; }
    __syncthreads();
    const int s0 = sb[0], s1 = sb[1];
    for (int i = s0 + tid; i < s1; i += 256)
        atomicAdd(&cnt[(bck[i] >> 19) & 63], 1);
    __syncthreads();
    if (tid < 64) {
        int c = cnt[tid];
        int x = c;
        #pragma unroll
        for (int o = 1; o < 64; o <<= 1) {
            int y = __shfl_up(x, o);
            if (tid >= o) x += y;
        }
        int excl = x - c;
        int gd = b * 64 + tid;
        if (gd < NN) {
            off[gd] = s0 + excl;
            invdeg[gd] = 1.0f / (float)max(c, 1);
        }
        cur[tid] = s0 + excl;
    }
    __syncthreads();
    for (int i = s0 + tid; i < s1; i += 256) {
        int pk = bck[i];
        int p = atomicAdd(&cur[(pk >> 19) & 63], 1);
        esrcF[p] = pk & 0x7FFFF;   // src | rel<<16
    }
}

// ---------------- prep: fp32 -> bf16 tables ----------------

__global__ void k_prep_x(const float* __restrict__ X, unsigned* __restrict__ Xt) {
    int i = blockIdx.x * blockDim.x + threadIdx.x;
    if (i < NN * 64) {
        float2 f = reinterpret_cast<const float2*>(X)[i];
        Xt[i] = pack2(f.x, f.y);
    }
}

__global__ void k_prep_wcat(const float* __restrict__ W0, const float* __restrict__ Wr,
                            __hip_bfloat16* __restrict__ dst) {
    int i = blockIdx.x * blockDim.x + threadIdx.x;
    if (i < 128 * 1152) {
        int n = i / 1152, k = i % 1152;
        float v = (k < 128) ? W0[k * 128 + n] : Wr[(k - 128) * 128 + n];
        reinterpret_cast<unsigned short*>(dst)[i] = (unsigned short)f2bf_rne(v);
    }
}

__global__ void k_prep_wt(const float* __restrict__ src, __hip_bfloat16* __restrict__ dst,
                          int K, int N) {
    int i = blockIdx.x * blockDim.x + threadIdx.x;
    if (i < N * K) {
        int n = i / K, k = i % K;
        reinterpret_cast<unsigned short*>(dst)[i] =
            (unsigned short)f2bf_rne(src[k * N + n]);
    }
}

// ---------------- aggregation: one wave per dst, merged segment ----------------

#define LOAD8                                                            \
    int p0 = __builtin_amdgcn_readfirstlane(esrcF[j]);                   \
    int p1 = __builtin_amdgcn_readfirstlane(esrcF[j + 1]);               \
    int p2 = __builtin_amdgcn_readfirstlane(esrcF[j + 2]);               \
    int p3 = __builtin_amdgcn_readfirstlane(esrcF[j + 3]);               \
    int p4 = __builtin_amdgcn_readfirstlane(esrcF[j + 4]);               \
    int p5 = __builtin_amdgcn_readfirstlane(esrcF[j + 5]);               \
    int p6 = __builtin_amdgcn_readfirstlane(esrcF[j + 6]);               \
    int p7 = __builtin_amdgcn_readfirstlane(esrcF[j + 7]);               \
    unsigned u0 = Xt[(unsigned)(p0 & 0xffff) * 64 + lane];               \
    unsigned u1 = Xt[(unsigned)(p1 & 0xffff) * 64 + lane];               \
    unsigned u2 = Xt[(unsigned)(p2 & 0xffff) * 64 + lane];               \
    unsigned u3 = Xt[(unsigned)(p3 & 0xffff) * 64 + lane];               \
    unsigned u4 = Xt[(unsigned)(p4 & 0xffff) * 64 + lane];               \
    unsigned u5 = Xt[(unsigned)(p5 & 0xffff) * 64 + lane];               \
    unsigned u6 = Xt[(unsigned)(p6 & 0xffff) * 64 + lane];               \
    unsigned u7 = Xt[(unsigned)(p7 & 0xffff) * 64 + lane];

// wide per-relation agg: AW[v][r*64+lane] = sum over rel-r in-edges of v
__global__ __launch_bounds__(256)
void k_aggw(const unsigned* __restrict__ Xt, unsigned* __restrict__ AW,
            const int* __restrict__ off, const int* __restrict__ esrcF) {
    const int wid = threadIdx.x >> 6, lane = threadIdx.x & 63;
    const int v = blockIdx.x * 4 + wid;
    if (v >= NN) return;
    const int s = off[v], e = off[v + 1];
    float l0 = 0, l1 = 0, l2 = 0, l3 = 0, l4 = 0, l5 = 0, l6 = 0, l7 = 0;
    float h0 = 0, h1 = 0, h2 = 0, h3 = 0, h4 = 0, h5 = 0, h6 = 0, h7 = 0;
#define ACCW(P, U)                                                       \
    do {                                                                 \
        float _lo = bflo(U), _hi = bfhi(U);                              \
        switch ((P) >> 16) {                                             \
            case 0: l0 += _lo; h0 += _hi; break;                         \
            case 1: l1 += _lo; h1 += _hi; break;                         \
            case 2: l2 += _lo; h2 += _hi; break;                         \
            case 3: l3 += _lo; h3 += _hi; break;                         \
            case 4: l4 += _lo; h4 += _hi; break;                         \
            case 5: l5 += _lo; h5 += _hi; break;                         \
            case 6: l6 += _lo; h6 += _hi; break;                         \
            default: l7 += _lo; h7 += _hi; break;                        \
        }                                                                \
    } while (0)
    for (int j = s; j < e; j += 8) {
        LOAD8
        ACCW(p0, u0);
        if (j + 1 < e) ACCW(p1, u1);
        if (j + 2 < e) ACCW(p2, u2);
        if (j + 3 < e) ACCW(p3, u3);
        if (j + 4 < e) ACCW(p4, u4);
        if (j + 5 < e) ACCW(p5, u5);
        if (j + 6 < e) ACCW(p6, u6);
        if (j + 7 < e) ACCW(p7, u7);
    }
#undef ACCW
    unsigned* o = AW + (size_t)v * 512 + lane;
    o[0]   = pack2(l0, h0);
    o[64]  = pack2(l1, h1);
    o[128] = pack2(l2, h2);
    o[192] = pack2(l3, h3);
    o[256] = pack2(l4, h4);
    o[320] = pack2(l5, h5);
    o[384] = pack2(l6, h6);
    o[448] = pack2(l7, h7);
}

// full-graph agg with invdeg scale: AH[v][lane] = (sum over all in-edges) * invdeg
__global__ __launch_bounds__(256)
void k_aggh(const unsigned* __restrict__ Xt, unsigned* __restrict__ AH,
            const int* __restrict__ off, const int* __restrict__ esrcF,
            const float* __restrict__ invdeg) {
    const int wid = threadIdx.x >> 6, lane = threadIdx.x & 63;
    const int v = blockIdx.x * 4 + wid;
    if (v >= NN) return;
    const int s = off[v], e = off[v + 1];
    float a0 = 0.f, a1 = 0.f;
    for (int j = s; j < e; j += 8) {
        LOAD8
        (void)p0;
        a0 += bflo(u0); a1 += bfhi(u0);
        if (j + 1 < e) { a0 += bflo(u1); a1 += bfhi(u1); }
        if (j + 2 < e) { a0 += bflo(u2); a1 += bfhi(u2); }
        if (j + 3 < e) { a0 += bflo(u3); a1 += bfhi(u3); }
        if (j + 4 < e) { a0 += bflo(u4); a1 += bfhi(u4); }
        if (j + 5 < e) { a0 += bflo(u5); a1 += bfhi(u5); }
        if (j + 6 < e) { a0 += bflo(u6); a1 += bfhi(u6); }
        if (j + 7 < e) { a0 += bflo(u7); a1 += bfhi(u7); }
    }
    float inv = invdeg[v];
    AH[(size_t)v * 64 + lane] = pack2(a0 * inv, a1 * inv);
}

// ---------------- bf16 MFMA GEMM, fused epilogues ----------------
// Y[M,N] = A[M,K] @ B[K,N]   (B pre-transposed: Bt [N][K] bf16)
// A: k<128 from A0 (stride 128), k>=128 from A1 (stride 1024, offset k-128)
// MODE 0 (rgcn):  v = relu(acc*invdeg[row]); Yf=v; Ybf=bf(v)
// MODE 1 (group): v = aux + alpha*(acc + bias); Ybf=bf(v)
// MODE 2 (final): Yf = acc + bias
template <int N, int MODE>
__global__ __launch_bounds__(256)
void k_mfma(const short* __restrict__ A0, const short* __restrict__ A1,
            const short* __restrict__ Bt, int K,
            float* __restrict__ Yf, unsigned short* __restrict__ Ybf,
            const float* __restrict__ aux, const float* __restrict__ bias,
            const float* __restrict__ alpha_p, const float* __restrict__ invdeg) {
    constexpr int NT = N / 16;
    const int w = threadIdx.x >> 6;
    const int lane = threadIdx.x & 63;
    const int lr = lane & 15;
    const int lk = (lane >> 4) * 8;
    const int rowBase = blockIdx.x * 64 + w * 16;
    const int r0 = min(rowBase + lr, NN - 1);

    f32x4 acc[NT];
    #pragma unroll
    for (int nt = 0; nt < NT; ++nt) acc[nt] = f32x4{0.f, 0.f, 0.f, 0.f};

    for (int k0 = 0; k0 < K; k0 += 32) {
        const short* ab; int astr, kk;
        if (k0 < 128) { ab = A0; astr = 128; kk = k0; }
        else          { ab = A1; astr = 1024; kk = k0 - 128; }
        bf16x8 a = *reinterpret_cast<const bf16x8*>(ab + (size_t)r0 * astr + kk + lk);
        #pragma unroll
        for (int nt = 0; nt < NT; ++nt) {
            bf16x8 b = *reinterpret_cast<const bf16x8*>(
                Bt + (size_t)(nt * 16 + lr) * K + k0 + lk);
            acc[nt] = __builtin_amdgcn_mfma_f32_16x16x32_bf16(a, b, acc[nt], 0, 0, 0);
        }
    }

    const float al = (MODE == 1) ? *alpha_p : 0.f;
    #pragma unroll
    for (int j = 0; j < 4; ++j) {
        const int row = rowBase + (lane >> 4) * 4 + j;
        if (row >= NN) continue;
        float idg = (MODE == 0) ? invdeg[row] : 0.f;
        #pragma unroll
        for (int nt = 0; nt < NT; ++nt) {
            const int col = nt * 16 + lr;
            float v = acc[nt][j];
            if (MODE == 0) {
                v = fmaxf(v * idg, 0.f);
                Yf[(size_t)row * 128 + col] = v;
                Ybf[(size_t)row * 128 + col] = (unsigned short)f2bf_rne(v);
            } else if (MODE == 1) {
                v = aux[(size_t)row * 128 + col] + al * (v + bias[col]);
                Ybf[(size_t)row * 128 + col] = (unsigned short)f2bf_rne(v);
            } else {
                Yf[(size_t)row * 64 + col] = v + bias[col];
            }
        }
    }
}

// ---------------- launch ----------------

extern "C" void kernel_launch(void* const* d_in, const int* in_sizes, int n_in,
                              void* d_out, int out_size, void* d_ws, size_t ws_size,
                              hipStream_t stream) {
    const float* X   = (const float*)d_in[0];
    const int*   ei  = (const int*)d_in[1];
    const int*   et  = (const int*)d_in[2];
    const float* W1  = (const float*)d_in[3];
    const float* W01 = (const float*)d_in[4];
    const float* al1 = (const float*)d_in[5];
    const float* p1w = (const float*)d_in[6];
    const float* p1b = (const float*)d_in[7];
    const float* W2  = (const float*)d_in[8];
    const float* W02 = (const float*)d_in[9];
    const float* al2 = (const float*)d_in[10];
    const float* p2w = (const float*)d_in[11];
    const float* p2b = (const float*)d_in[12];
    const float* ow  = (const float*)d_in[13];
    const float* ob  = (const float*)d_in[14];
    float* out = (float*)d_out;

    char* wsp = (char*)d_ws;
    size_t o = 0;
    auto take = [&](size_t bytes) -> void* {
        void* p = wsp + o;
        o = (o + bytes + 255) & ~(size_t)255;
        return p;
    };
    int*      ccnt   = (int*)take((size_t)NCB * 4);
    int*      cbase  = (int*)take((size_t)(NCB + 1) * 4);
    int*      ccur   = (int*)take((size_t)NCB * 4);
    int*      off    = (int*)take((size_t)(NN + 1) * 4);
    float*    invdeg = (float*)take((size_t)NN * 4);
    int*      bck    = (int*)take((size_t)NE * 4);
    int*      esrcF  = (int*)take((size_t)(NE + 8) * 4);     // +8 overread slack
    unsigned* T1     = (unsigned*)take((size_t)NN * 64 * 4); // Xbf  -> H2bf
    unsigned* T2     = (unsigned*)take((size_t)NN * 64 * 4); // Hbf  -> G2bf
    unsigned* T3     = (unsigned*)take((size_t)NN * 64 * 4); // G1bf
    unsigned* AW     = (unsigned*)take((size_t)NN * 512 * 4);
    unsigned* AH     = (unsigned*)take((size_t)NN * 64 * 4);
    float*    Hf     = (float*)take((size_t)NN * 128 * 4);
    __hip_bfloat16* WtC1 = (__hip_bfloat16*)take((size_t)128 * 1152 * 2);
    __hip_bfloat16* WtC2 = (__hip_bfloat16*)take((size_t)128 * 1152 * 2);
    __hip_bfloat16* Wtp1 = (__hip_bfloat16*)take((size_t)128 * 128 * 2);
    __hip_bfloat16* Wtp2 = (__hip_bfloat16*)take((size_t)128 * 128 * 2);
    __hip_bfloat16* WtO  = (__hip_bfloat16*)take((size_t)64 * 128 * 2);
    if (o > ws_size) return;

    // ---- CSR build (dst-keyed, rel in payload) ----
    hipMemsetAsync(ccnt, 0, (size_t)NCB * 4, stream);
    k_chist<<<256, 1024, 0, stream>>>(ei, ccnt);
    k_cscan<<<1, 1024, 0, stream>>>(ccnt, cbase, ccur, off);
    k_cscatter<<<256, 1024, 0, stream>>>(ei, et, ccur, bck);
    k_build<<<NCB, 256, 0, stream>>>(bck, cbase, off, invdeg, esrcF);

    // ---- prep ----
    k_prep_x<<<(NN * 64 + 255) / 256, 256, 0, stream>>>(X, T1);
    k_prep_wcat<<<(128 * 1152 + 255) / 256, 256, 0, stream>>>(W01, W1, WtC1);
    k_prep_wcat<<<(128 * 1152 + 255) / 256, 256, 0, stream>>>(W02, W2, WtC2);
    k_prep_wt<<<(128 * 128 + 255) / 256, 256, 0, stream>>>(p1w, Wtp1, 128, 128);
    k_prep_wt<<<(128 * 128 + 255) / 256, 256, 0, stream>>>(p2w, Wtp2, 128, 128);
    k_prep_wt<<<(64 * 128 + 255) / 256, 256, 0, stream>>>(ow, WtO, 128, 64);

    const int GAGG = (NN + 3) / 4;   // 12500 blocks, wave per node

    // ---- layer 1 ----
    k_aggw<<<GAGG, 256, 0, stream>>>(T1, AW, off, esrcF);
    k_mfma<128, 0><<<GRIDM, 256, 0, stream>>>(
        (const short*)T1, (const short*)AW, (const short*)WtC1, 1152,
        Hf, (unsigned short*)T2, nullptr, nullptr, nullptr, invdeg);
    k_aggh<<<GAGG, 256, 0, stream>>>(T2, AH, off, esrcF, invdeg);
    k_mfma<128, 1><<<GRIDM, 256, 0, stream>>>(
        (const short*)AH, nullptr, (const short*)Wtp1, 128,
        nullptr, (unsigned short*)T3, Hf, p1b, al1, nullptr);

    // ---- layer 2 ----
    k_aggw<<<GAGG, 256, 0, stream>>>(T3, AW, off, esrcF);
    k_mfma<128, 0><<<GRIDM, 256, 0, stream>>>(
        (const short*)T3, (const short*)AW, (const short*)WtC2, 1152,
        Hf, (unsigned short*)T1, nullptr, nullptr, nullptr, invdeg);
    k_aggh<<<GAGG, 256, 0, stream>>>(T1, AH, off, esrcF, invdeg);
    k_mfma<128, 1><<<GRIDM, 256, 0, stream>>>(
        (const short*)AH, nullptr, (const short*)Wtp2, 128,
        nullptr, (unsigned short*)T2, Hf, p2b, al2, nullptr);

    // ---- final projection ----
    k_mfma<64, 2><<<GRIDM, 256, 0, stream>>>(
        (const short*)T2, nullptr, (const short*)WtO, 128,
        out, nullptr, nullptr, ob, nullptr, nullptr);
}

// Round 6
// 807.603 us; speedup vs baseline: 1.4441x; 1.4441x over previous
//
#include <hip/hip_runtime.h>
#include <hip/hip_bf16.h>

#define NN 50000
#define NE 1600000
#define NR 8
#define D 128
#define DOUT 64
#define NCB ((NN + 63) / 64)          // 782 coarse buckets (dst>>6)
#define NBLK 256                      // partition blocks
#define CH ((NE + NBLK - 1) / NBLK)   // 6250 edges per partition block
#define GRIDM ((NN + 63) / 64)        // 782 M-tiles for MFMA GEMM

typedef __attribute__((ext_vector_type(8))) __bf16 bf16x8;
typedef __attribute__((ext_vector_type(4))) float f32x4;

__device__ __forceinline__ float bflo(unsigned u) { return __uint_as_float(u << 16); }
__device__ __forceinline__ float bfhi(unsigned u) { return __uint_as_float(u & 0xffff0000u); }
__device__ __forceinline__ unsigned f2bf_rne(float x) {
    unsigned u = __float_as_uint(x);
    return (u + 0x7fffu + ((u >> 16) & 1u)) >> 16;
}
__device__ __forceinline__ unsigned pack2(float a, float b) {
    return f2bf_rne(a) | (f2bf_rne(b) << 16);
}

// ---------------- CSR build: atomic-free radix partition ----------------
// P1: per-block LDS hist -> cntmat[bucket*NBLK + blk]
__global__ __launch_bounds__(1024)
void k_cnt(const int* __restrict__ ei, int* __restrict__ cntmat) {
    __shared__ int h[NCB];
    const int blk = blockIdx.x, tid = threadIdx.x;
    for (int i = tid; i < NCB; i += 1024) h[i] = 0;
    __syncthreads();
    const int e0 = blk * CH, e1 = min(e0 + CH, NE);
    for (int e = e0 + tid; e < e1; e += 1024)
        atomicAdd(&h[ei[NE + e] >> 6], 1);
    __syncthreads();
    for (int i = tid; i < NCB; i += 1024) cntmat[i * NBLK + blk] = h[i];
}

// P2: per-bucket exclusive scan over the 256 block counts (1 wave per bucket)
__global__ __launch_bounds__(64)
void k_colscan(int* __restrict__ cntmat, int* __restrict__ colsum) {
    const int b = blockIdx.x, lane = threadIdx.x;
    int4 v = *reinterpret_cast<int4*>(cntmat + b * NBLK + lane * 4);
    int s = v.x + v.y + v.z + v.w;
    int e = s;
    #pragma unroll
    for (int o = 1; o < 64; o <<= 1) {
        int y = __shfl_up(e, o);
        if (lane >= o) e += y;
    }
    int excl = e - s;
    int4 w;
    w.x = excl; w.y = excl + v.x; w.z = excl + v.x + v.y; w.w = excl + v.x + v.y + v.z;
    *reinterpret_cast<int4*>(cntmat + b * NBLK + lane * 4) = w;
    if (lane == 63) colsum[b] = e;
}

// P3: exclusive scan of bucket totals -> bstart
__global__ __launch_bounds__(1024)
void k_bscan(const int* __restrict__ colsum, int* __restrict__ bstart,
             int* __restrict__ off) {
    __shared__ int s[1024];
    int t = threadIdx.x;
    int v = (t < NCB) ? colsum[t] : 0;
    s[t] = v;
    __syncthreads();
    for (int o = 1; o < 1024; o <<= 1) {
        int x = (t >= o) ? s[t - o] : 0;
        __syncthreads();
        s[t] += x;
        __syncthreads();
    }
    if (t < NCB) bstart[t] = s[t] - v;
    if (t == 0) { bstart[NCB] = NE; off[NN] = NE; }
}

// P4: scatter into bck; position = bstart[bucket] + block-prefix + LDS rank
// pack: dstlo(6) << 19 | rel(3) << 16 | src(16)
__global__ __launch_bounds__(1024)
void k_pscatter(const int* __restrict__ ei, const int* __restrict__ et,
                const int* __restrict__ cntmat, const int* __restrict__ bstart,
                int* __restrict__ bck) {
    __shared__ int cur[NCB];
    const int blk = blockIdx.x, tid = threadIdx.x;
    for (int i = tid; i < NCB; i += 1024)
        cur[i] = bstart[i] + cntmat[i * NBLK + blk];
    __syncthreads();
    const int e0 = blk * CH, e1 = min(e0 + CH, NE);
    for (int e = e0 + tid; e < e1; e += 1024) {
        int dst = ei[NE + e];
        int pk = ((dst & 63) << 19) | (et[e] << 16) | ei[e];
        int p = atomicAdd(&cur[dst >> 6], 1);
        bck[p] = pk;
    }
}

// per coarse bucket: per-dst counts (LDS), scan, write off/invdeg, local scatter
__global__ __launch_bounds__(256)
void k_build(const int* __restrict__ bck, const int* __restrict__ cbase,
             int* __restrict__ off, float* __restrict__ invdeg,
             int* __restrict__ esrcF) {
    __shared__ int cnt[64];
    __shared__ int cur[64];
    __shared__ int sb[2];
    const int b = blockIdx.x;
    const int tid = threadIdx.x;
    if (tid < 64) cnt[tid] = 0;
    if (tid == 0) { sb[0] = cbase[b]; sb[1] = cbase[b + 1]; }
    __syncthreads();
    const int s0 = sb[0], s1 = sb[1];
    for (int i = s0 + tid; i < s1; i += 256)
        atomicAdd(&cnt[(bck[i] >> 19) & 63], 1);
    __syncthreads();
    if (tid < 64) {
        int c = cnt[tid];
        int x = c;
        #pragma unroll
        for (int o = 1; o < 64; o <<= 1) {
            int y = __shfl_up(x, o);
            if (tid >= o) x += y;
        }
        int excl = x - c;
        int gd = b * 64 + tid;
        if (gd < NN) {
            off[gd] = s0 + excl;
            invdeg[gd] = 1.0f / (float)max(c, 1);
        }
        cur[tid] = s0 + excl;
    }
    __syncthreads();
    for (int i = s0 + tid; i < s1; i += 256) {
        int pk = bck[i];
        int p = atomicAdd(&cur[(pk >> 19) & 63], 1);
        esrcF[p] = pk & 0x7FFFF;   // src | rel<<16
    }
}

// ---------------- prep: fp32 -> bf16 tables ----------------

__global__ void k_prep_x(const float* __restrict__ X, unsigned* __restrict__ Xt) {
    int i = blockIdx.x * blockDim.x + threadIdx.x;
    if (i < NN * 64) {
        float2 f = reinterpret_cast<const float2*>(X)[i];
        Xt[i] = pack2(f.x, f.y);
    }
}

__global__ void k_prep_wcat(const float* __restrict__ W0, const float* __restrict__ Wr,
                            __hip_bfloat16* __restrict__ dst) {
    int i = blockIdx.x * blockDim.x + threadIdx.x;
    if (i < 128 * 1152) {
        int n = i / 1152, k = i % 1152;
        float v = (k < 128) ? W0[k * 128 + n] : Wr[(k - 128) * 128 + n];
        reinterpret_cast<unsigned short*>(dst)[i] = (unsigned short)f2bf_rne(v);
    }
}

__global__ void k_prep_wt(const float* __restrict__ src, __hip_bfloat16* __restrict__ dst,
                          int K, int N) {
    int i = blockIdx.x * blockDim.x + threadIdx.x;
    if (i < N * K) {
        int n = i / K, k = i % K;
        reinterpret_cast<unsigned short*>(dst)[i] =
            (unsigned short)f2bf_rne(src[k * N + n]);
    }
}

// ---------------- aggregation: one wave per dst, merged segment ----------------

#define LOAD8                                                            \
    int p0 = __builtin_amdgcn_readfirstlane(esrcF[j]);                   \
    int p1 = __builtin_amdgcn_readfirstlane(esrcF[j + 1]);               \
    int p2 = __builtin_amdgcn_readfirstlane(esrcF[j + 2]);               \
    int p3 = __builtin_amdgcn_readfirstlane(esrcF[j + 3]);               \
    int p4 = __builtin_amdgcn_readfirstlane(esrcF[j + 4]);               \
    int p5 = __builtin_amdgcn_readfirstlane(esrcF[j + 5]);               \
    int p6 = __builtin_amdgcn_readfirstlane(esrcF[j + 6]);               \
    int p7 = __builtin_amdgcn_readfirstlane(esrcF[j + 7]);               \
    unsigned u0 = Xt[(unsigned)(p0 & 0xffff) * 64 + lane];               \
    unsigned u1 = Xt[(unsigned)(p1 & 0xffff) * 64 + lane];               \
    unsigned u2 = Xt[(unsigned)(p2 & 0xffff) * 64 + lane];               \
    unsigned u3 = Xt[(unsigned)(p3 & 0xffff) * 64 + lane];               \
    unsigned u4 = Xt[(unsigned)(p4 & 0xffff) * 64 + lane];               \
    unsigned u5 = Xt[(unsigned)(p5 & 0xffff) * 64 + lane];               \
    unsigned u6 = Xt[(unsigned)(p6 & 0xffff) * 64 + lane];               \
    unsigned u7 = Xt[(unsigned)(p7 & 0xffff) * 64 + lane];

// wide per-relation agg: AW[v][r*64+lane] = sum over rel-r in-edges of v
__global__ __launch_bounds__(256)
void k_aggw(const unsigned* __restrict__ Xt, unsigned* __restrict__ AW,
            const int* __restrict__ off, const int* __restrict__ esrcF) {
    const int wid = threadIdx.x >> 6, lane = threadIdx.x & 63;
    const int v = blockIdx.x * 4 + wid;
    if (v >= NN) return;
    const int s = off[v], e = off[v + 1];
    float l0 = 0, l1 = 0, l2 = 0, l3 = 0, l4 = 0, l5 = 0, l6 = 0, l7 = 0;
    float h0 = 0, h1 = 0, h2 = 0, h3 = 0, h4 = 0, h5 = 0, h6 = 0, h7 = 0;
#define ACCW(P, U)                                                       \
    do {                                                                 \
        float _lo = bflo(U), _hi = bfhi(U);                              \
        switch ((P) >> 16) {                                             \
            case 0: l0 += _lo; h0 += _hi; break;                         \
            case 1: l1 += _lo; h1 += _hi; break;                         \
            case 2: l2 += _lo; h2 += _hi; break;                         \
            case 3: l3 += _lo; h3 += _hi; break;                         \
            case 4: l4 += _lo; h4 += _hi; break;                         \
            case 5: l5 += _lo; h5 += _hi; break;                         \
            case 6: l6 += _lo; h6 += _hi; break;                         \
            default: l7 += _lo; h7 += _hi; break;                        \
        }                                                                \
    } while (0)
    for (int j = s; j < e; j += 8) {
        LOAD8
        ACCW(p0, u0);
        if (j + 1 < e) ACCW(p1, u1);
        if (j + 2 < e) ACCW(p2, u2);
        if (j + 3 < e) ACCW(p3, u3);
        if (j + 4 < e) ACCW(p4, u4);
        if (j + 5 < e) ACCW(p5, u5);
        if (j + 6 < e) ACCW(p6, u6);
        if (j + 7 < e) ACCW(p7, u7);
    }
#undef ACCW
    unsigned* o = AW + (size_t)v * 512 + lane;
    o[0]   = pack2(l0, h0);
    o[64]  = pack2(l1, h1);
    o[128] = pack2(l2, h2);
    o[192] = pack2(l3, h3);
    o[256] = pack2(l4, h4);
    o[320] = pack2(l5, h5);
    o[384] = pack2(l6, h6);
    o[448] = pack2(l7, h7);
}

// full-graph agg with invdeg scale: AH[v][lane] = (sum over all in-edges) * invdeg
__global__ __launch_bounds__(256)
void k_aggh(const unsigned* __restrict__ Xt, unsigned* __restrict__ AH,
            const int* __restrict__ off, const int* __restrict__ esrcF,
            const float* __restrict__ invdeg) {
    const int wid = threadIdx.x >> 6, lane = threadIdx.x & 63;
    const int v = blockIdx.x * 4 + wid;
    if (v >= NN) return;
    const int s = off[v], e = off[v + 1];
    float a0 = 0.f, a1 = 0.f;
    for (int j = s; j < e; j += 8) {
        LOAD8
        (void)p0;
        a0 += bflo(u0); a1 += bfhi(u0);
        if (j + 1 < e) { a0 += bflo(u1); a1 += bfhi(u1); }
        if (j + 2 < e) { a0 += bflo(u2); a1 += bfhi(u2); }
        if (j + 3 < e) { a0 += bflo(u3); a1 += bfhi(u3); }
        if (j + 4 < e) { a0 += bflo(u4); a1 += bfhi(u4); }
        if (j + 5 < e) { a0 += bflo(u5); a1 += bfhi(u5); }
        if (j + 6 < e) { a0 += bflo(u6); a1 += bfhi(u6); }
        if (j + 7 < e) { a0 += bflo(u7); a1 += bfhi(u7); }
    }
    float inv = invdeg[v];
    AH[(size_t)v * 64 + lane] = pack2(a0 * inv, a1 * inv);
}

// ---------------- bf16 MFMA GEMM, fused epilogues ----------------
// Y[M,N] = A[M,K] @ B[K,N]   (B pre-transposed: Bt [N][K] bf16)
// A: k<128 from A0 (stride 128), k>=128 from A1 (stride 1024, offset k-128)
// MODE 0 (rgcn):  v = relu(acc*invdeg[row]); Yf=v; Ybf=bf(v)
// MODE 1 (group): v = aux + alpha*(acc + bias); Ybf=bf(v)
// MODE 2 (final): Yf = acc + bias
template <int N, int MODE>
__global__ __launch_bounds__(256)
void k_mfma(const short* __restrict__ A0, const short* __restrict__ A1,
            const short* __restrict__ Bt, int K,
            float* __restrict__ Yf, unsigned short* __restrict__ Ybf,
            const float* __restrict__ aux, const float* __restrict__ bias,
            const float* __restrict__ alpha_p, const float* __restrict__ invdeg) {
    constexpr int NT = N / 16;
    const int w = threadIdx.x >> 6;
    const int lane = threadIdx.x & 63;
    const int lr = lane & 15;
    const int lk = (lane >> 4) * 8;
    const int rowBase = blockIdx.x * 64 + w * 16;
    const int r0 = min(rowBase + lr, NN - 1);

    f32x4 acc[NT];
    #pragma unroll
    for (int nt = 0; nt < NT; ++nt) acc[nt] = f32x4{0.f, 0.f, 0.f, 0.f};

    for (int k0 = 0; k0 < K; k0 += 32) {
        const short* ab; int astr, kk;
        if (k0 < 128) { ab = A0; astr = 128; kk = k0; }
        else          { ab = A1; astr = 1024; kk = k0 - 128; }
        bf16x8 a = *reinterpret_cast<const bf16x8*>(ab + (size_t)r0 * astr + kk + lk);
        #pragma unroll
        for (int nt = 0; nt < NT; ++nt) {
            bf16x8 b = *reinterpret_cast<const bf16x8*>(
                Bt + (size_t)(nt * 16 + lr) * K + k0 + lk);
            acc[nt] = __builtin_amdgcn_mfma_f32_16x16x32_bf16(a, b, acc[nt], 0, 0, 0);
        }
    }

    const float al = (MODE == 1) ? *alpha_p : 0.f;
    #pragma unroll
    for (int j = 0; j < 4; ++j) {
        const int row = rowBase + (lane >> 4) * 4 + j;
        if (row >= NN) continue;
        float idg = (MODE == 0) ? invdeg[row] : 0.f;
        #pragma unroll
        for (int nt = 0; nt < NT; ++nt) {
            const int col = nt * 16 + lr;
            float v = acc[nt][j];
            if (MODE == 0) {
                v = fmaxf(v * idg, 0.f);
                Yf[(size_t)row * 128 + col] = v;
                Ybf[(size_t)row * 128 + col] = (unsigned short)f2bf_rne(v);
            } else if (MODE == 1) {
                v = aux[(size_t)row * 128 + col] + al * (v + bias[col]);
                Ybf[(size_t)row * 128 + col] = (unsigned short)f2bf_rne(v);
            } else {
                Yf[(size_t)row * 64 + col] = v + bias[col];
            }
        }
    }
}

// ---------------- launch ----------------

extern "C" void kernel_launch(void* const* d_in, const int* in_sizes, int n_in,
                              void* d_out, int out_size, void* d_ws, size_t ws_size,
                              hipStream_t stream) {
    const float* X   = (const float*)d_in[0];
    const int*   ei  = (const int*)d_in[1];
    const int*   et  = (const int*)d_in[2];
    const float* W1  = (const float*)d_in[3];
    const float* W01 = (const float*)d_in[4];
    const float* al1 = (const float*)d_in[5];
    const float* p1w = (const float*)d_in[6];
    const float* p1b = (const float*)d_in[7];
    const float* W2  = (const float*)d_in[8];
    const float* W02 = (const float*)d_in[9];
    const float* al2 = (const float*)d_in[10];
    const float* p2w = (const float*)d_in[11];
    const float* p2b = (const float*)d_in[12];
    const float* ow  = (const float*)d_in[13];
    const float* ob  = (const float*)d_in[14];
    float* out = (float*)d_out;

    char* wsp = (char*)d_ws;
    size_t o = 0;
    auto take = [&](size_t bytes) -> void* {
        void* p = wsp + o;
        o = (o + bytes + 255) & ~(size_t)255;
        return p;
    };
    int*      cntmat = (int*)take((size_t)NCB * NBLK * 4);
    int*      colsum = (int*)take((size_t)NCB * 4);
    int*      bstart = (int*)take((size_t)(NCB + 1) * 4);
    int*      off    = (int*)take((size_t)(NN + 1) * 4);
    float*    invdeg = (float*)take((size_t)NN * 4);
    int*      bck    = (int*)take((size_t)NE * 4);
    int*      esrcF  = (int*)take((size_t)(NE + 8) * 4);     // +8 overread slack
    unsigned* T1     = (unsigned*)take((size_t)NN * 64 * 4); // Xbf  -> H2bf
    unsigned* T2     = (unsigned*)take((size_t)NN * 64 * 4); // Hbf  -> G2bf
    unsigned* T3     = (unsigned*)take((size_t)NN * 64 * 4); // G1bf
    unsigned* AW     = (unsigned*)take((size_t)NN * 512 * 4);
    unsigned* AH     = (unsigned*)take((size_t)NN * 64 * 4);
    float*    Hf     = (float*)take((size_t)NN * 128 * 4);
    __hip_bfloat16* WtC1 = (__hip_bfloat16*)take((size_t)128 * 1152 * 2);
    __hip_bfloat16* WtC2 = (__hip_bfloat16*)take((size_t)128 * 1152 * 2);
    __hip_bfloat16* Wtp1 = (__hip_bfloat16*)take((size_t)128 * 128 * 2);
    __hip_bfloat16* Wtp2 = (__hip_bfloat16*)take((size_t)128 * 128 * 2);
    __hip_bfloat16* WtO  = (__hip_bfloat16*)take((size_t)64 * 128 * 2);
    if (o > ws_size) return;

    // ---- CSR build (atomic-free radix partition; dst-keyed, rel in payload) ----
    k_cnt<<<NBLK, 1024, 0, stream>>>(ei, cntmat);
    k_colscan<<<NCB, 64, 0, stream>>>(cntmat, colsum);
    k_bscan<<<1, 1024, 0, stream>>>(colsum, bstart, off);
    k_pscatter<<<NBLK, 1024, 0, stream>>>(ei, et, cntmat, bstart, bck);
    k_build<<<NCB, 256, 0, stream>>>(bck, bstart, off, invdeg, esrcF);

    // ---- prep ----
    k_prep_x<<<(NN * 64 + 255) / 256, 256, 0, stream>>>(X, T1);
    k_prep_wcat<<<(128 * 1152 + 255) / 256, 256, 0, stream>>>(W01, W1, WtC1);
    k_prep_wcat<<<(128 * 1152 + 255) / 256, 256, 0, stream>>>(W02, W2, WtC2);
    k_prep_wt<<<(128 * 128 + 255) / 256, 256, 0, stream>>>(p1w, Wtp1, 128, 128);
    k_prep_wt<<<(128 * 128 + 255) / 256, 256, 0, stream>>>(p2w, Wtp2, 128, 128);
    k_prep_wt<<<(64 * 128 + 255) / 256, 256, 0, stream>>>(ow, WtO, 128, 64);

    const int GAGG = (NN + 3) / 4;   // 12500 blocks, wave per node

    // ---- layer 1 ----
    k_aggw<<<GAGG, 256, 0, stream>>>(T1, AW, off, esrcF);
    k_mfma<128, 0><<<GRIDM, 256, 0, stream>>>(
        (const short*)T1, (const short*)AW, (const short*)WtC1, 1152,
        Hf, (unsigned short*)T2, nullptr, nullptr, nullptr, invdeg);
    k_aggh<<<GAGG, 256, 0, stream>>>(T2, AH, off, esrcF, invdeg);
    k_mfma<128, 1><<<GRIDM, 256, 0, stream>>>(
        (const short*)AH, nullptr, (const short*)Wtp1, 128,
        nullptr, (unsigned short*)T3, Hf, p1b, al1, nullptr);

    // ---- layer 2 ----
    k_aggw<<<GAGG, 256, 0, stream>>>(T3, AW, off, esrcF);
    k_mfma<128, 0><<<GRIDM, 256, 0, stream>>>(
        (const short*)T3, (const short*)AW, (const short*)WtC2, 1152,
        Hf, (unsigned short*)T1, nullptr, nullptr, nullptr, invdeg);
    k_aggh<<<GAGG, 256, 0, stream>>>(T1, AH, off, esrcF, invdeg);
    k_mfma<128, 1><<<GRIDM, 256, 0, stream>>>(
        (const short*)AH, nullptr, (const short*)Wtp2, 128,
        nullptr, (unsigned short*)T2, Hf, p2b, al2, nullptr);

    // ---- final projection ----
    k_mfma<64, 2><<<GRIDM, 256, 0, stream>>>(
        (const short*)T2, nullptr, (const short*)WtO, 128,
        out, nullptr, nullptr, ob, nullptr, nullptr);
}

// Round 7
// 562.296 us; speedup vs baseline: 2.0740x; 1.4363x over previous
//
#include <hip/hip_runtime.h>
#include <hip/hip_bf16.h>

#define NN 50000
#define NE 1600000
#define NR 8
#define D 128
#define DOUT 64
#define NCB ((NN + 63) / 64)          // 782 coarse buckets (dst>>6)
#define NBLK 256                      // partition blocks
#define CH ((NE + NBLK - 1) / NBLK)   // 6250 edges per partition block
#define GRIDM ((NN + 63) / 64)        // 782 M-tiles for MFMA GEMM

typedef __attribute__((ext_vector_type(8))) __bf16 bf16x8;
typedef __attribute__((ext_vector_type(4))) float f32x4;

__device__ __forceinline__ float bflo(unsigned u) { return __uint_as_float(u << 16); }
__device__ __forceinline__ float bfhi(unsigned u) { return __uint_as_float(u & 0xffff0000u); }
__device__ __forceinline__ unsigned f2bf_rne(float x) {
    unsigned u = __float_as_uint(x);
    return (u + 0x7fffu + ((u >> 16) & 1u)) >> 16;
}
__device__ __forceinline__ unsigned pack2(float a, float b) {
    return f2bf_rne(a) | (f2bf_rne(b) << 16);
}

// async global->LDS, 16B per lane; LDS dest = wave-uniform base + lane*16
__device__ __forceinline__ void gl2lds16(const void* g, void* l) {
    __builtin_amdgcn_global_load_lds(
        (const __attribute__((address_space(1))) unsigned int*)g,
        (__attribute__((address_space(3))) unsigned int*)l, 16, 0, 0);
}

// ---------------- CSR build: atomic-free radix partition ----------------
__global__ __launch_bounds__(1024)
void k_cnt(const int* __restrict__ ei, int* __restrict__ cntmat) {
    __shared__ int h[NCB];
    const int blk = blockIdx.x, tid = threadIdx.x;
    for (int i = tid; i < NCB; i += 1024) h[i] = 0;
    __syncthreads();
    const int e0 = blk * CH, e1 = min(e0 + CH, NE);
    for (int e = e0 + tid; e < e1; e += 1024)
        atomicAdd(&h[ei[NE + e] >> 6], 1);
    __syncthreads();
    for (int i = tid; i < NCB; i += 1024) cntmat[i * NBLK + blk] = h[i];
}

__global__ __launch_bounds__(64)
void k_colscan(int* __restrict__ cntmat, int* __restrict__ colsum) {
    const int b = blockIdx.x, lane = threadIdx.x;
    int4 v = *reinterpret_cast<int4*>(cntmat + b * NBLK + lane * 4);
    int s = v.x + v.y + v.z + v.w;
    int e = s;
    #pragma unroll
    for (int o = 1; o < 64; o <<= 1) {
        int y = __shfl_up(e, o);
        if (lane >= o) e += y;
    }
    int excl = e - s;
    int4 w;
    w.x = excl; w.y = excl + v.x; w.z = excl + v.x + v.y; w.w = excl + v.x + v.y + v.z;
    *reinterpret_cast<int4*>(cntmat + b * NBLK + lane * 4) = w;
    if (lane == 63) colsum[b] = e;
}

__global__ __launch_bounds__(1024)
void k_bscan(const int* __restrict__ colsum, int* __restrict__ bstart,
             int* __restrict__ off) {
    __shared__ int s[1024];
    int t = threadIdx.x;
    int v = (t < NCB) ? colsum[t] : 0;
    s[t] = v;
    __syncthreads();
    for (int o = 1; o < 1024; o <<= 1) {
        int x = (t >= o) ? s[t - o] : 0;
        __syncthreads();
        s[t] += x;
        __syncthreads();
    }
    if (t < NCB) bstart[t] = s[t] - v;
    if (t == 0) { bstart[NCB] = NE; off[NN] = NE; }
}

// pack: dstlo(6) << 19 | rel(3) << 16 | src(16)
__global__ __launch_bounds__(1024)
void k_pscatter(const int* __restrict__ ei, const int* __restrict__ et,
                const int* __restrict__ cntmat, const int* __restrict__ bstart,
                int* __restrict__ bck) {
    __shared__ int cur[NCB];
    const int blk = blockIdx.x, tid = threadIdx.x;
    for (int i = tid; i < NCB; i += 1024)
        cur[i] = bstart[i] + cntmat[i * NBLK + blk];
    __syncthreads();
    const int e0 = blk * CH, e1 = min(e0 + CH, NE);
    for (int e = e0 + tid; e < e1; e += 1024) {
        int dst = ei[NE + e];
        int pk = ((dst & 63) << 19) | (et[e] << 16) | ei[e];
        int p = atomicAdd(&cur[dst >> 6], 1);
        bck[p] = pk;
    }
}

__global__ __launch_bounds__(256)
void k_build(const int* __restrict__ bck, const int* __restrict__ cbase,
             int* __restrict__ off, float* __restrict__ invdeg,
             int* __restrict__ esrcF) {
    __shared__ int cnt[64];
    __shared__ int cur[64];
    __shared__ int sb[2];
    const int b = blockIdx.x;
    const int tid = threadIdx.x;
    if (tid < 64) cnt[tid] = 0;
    if (tid == 0) { sb[0] = cbase[b]; sb[1] = cbase[b + 1]; }
    __syncthreads();
    const int s0 = sb[0], s1 = sb[1];
    for (int i = s0 + tid; i < s1; i += 256)
        atomicAdd(&cnt[(bck[i] >> 19) & 63], 1);
    __syncthreads();
    if (tid < 64) {
        int c = cnt[tid];
        int x = c;
        #pragma unroll
        for (int o = 1; o < 64; o <<= 1) {
            int y = __shfl_up(x, o);
            if (tid >= o) x += y;
        }
        int excl = x - c;
        int gd = b * 64 + tid;
        if (gd < NN) {
            off[gd] = s0 + excl;
            invdeg[gd] = 1.0f / (float)max(c, 1);
        }
        cur[tid] = s0 + excl;
    }
    __syncthreads();
    for (int i = s0 + tid; i < s1; i += 256) {
        int pk = bck[i];
        int p = atomicAdd(&cur[(pk >> 19) & 63], 1);
        esrcF[p] = pk & 0x7FFFF;   // src | rel<<16
    }
}

// ---------------- prep: fp32 -> bf16 tables (weights: chunk-blocked + XOR-swizzled) --

__global__ void k_prep_x(const float* __restrict__ X, unsigned* __restrict__ Xt) {
    int i = blockIdx.x * blockDim.x + threadIdx.x;
    if (i < NN * 64) {
        float2 f = reinterpret_cast<const float2*>(X)[i];
        Xt[i] = pack2(f.x, f.y);
    }
}

// dst layout: [kc][n][e] where e = (k&127) ^ ((n&7)<<3)  (inverse-swizzled source
// so global_load_lds' linear LDS write + swizzled ds_read compose correctly)
__global__ void k_prep_wcat(const float* __restrict__ W0, const float* __restrict__ Wr,
                            unsigned short* __restrict__ dst) {
    int i = blockIdx.x * blockDim.x + threadIdx.x;
    if (i < 128 * 1152) {
        int n = i / 1152, k = i % 1152;
        float v = (k < 128) ? W0[k * 128 + n] : Wr[(k - 128) * 128 + n];
        int kc = k >> 7, kl = k & 127;
        int e = kl ^ ((n & 7) << 3);
        dst[((size_t)kc * 128 + n) * 128 + e] = (unsigned short)f2bf_rne(v);
    }
}

// src [128][N] f32 -> dst [N][128] bf16, swizzled: dst[n][k ^ ((n&7)<<3)]
__global__ void k_prep_wt(const float* __restrict__ src, unsigned short* __restrict__ dst,
                          int N) {
    int i = blockIdx.x * blockDim.x + threadIdx.x;
    if (i < N * 128) {
        int n = i >> 7, k = i & 127;
        int e = k ^ ((n & 7) << 3);
        dst[n * 128 + e] = (unsigned short)f2bf_rne(src[k * N + n]);
    }
}

// ---------------- aggregation: one wave per dst, merged segment ----------------

#define LOAD8                                                            \
    int p0 = __builtin_amdgcn_readfirstlane(esrcF[j]);                   \
    int p1 = __builtin_amdgcn_readfirstlane(esrcF[j + 1]);               \
    int p2 = __builtin_amdgcn_readfirstlane(esrcF[j + 2]);               \
    int p3 = __builtin_amdgcn_readfirstlane(esrcF[j + 3]);               \
    int p4 = __builtin_amdgcn_readfirstlane(esrcF[j + 4]);               \
    int p5 = __builtin_amdgcn_readfirstlane(esrcF[j + 5]);               \
    int p6 = __builtin_amdgcn_readfirstlane(esrcF[j + 6]);               \
    int p7 = __builtin_amdgcn_readfirstlane(esrcF[j + 7]);               \
    unsigned u0 = Xt[(unsigned)(p0 & 0xffff) * 64 + lane];               \
    unsigned u1 = Xt[(unsigned)(p1 & 0xffff) * 64 + lane];               \
    unsigned u2 = Xt[(unsigned)(p2 & 0xffff) * 64 + lane];               \
    unsigned u3 = Xt[(unsigned)(p3 & 0xffff) * 64 + lane];               \
    unsigned u4 = Xt[(unsigned)(p4 & 0xffff) * 64 + lane];               \
    unsigned u5 = Xt[(unsigned)(p5 & 0xffff) * 64 + lane];               \
    unsigned u6 = Xt[(unsigned)(p6 & 0xffff) * 64 + lane];               \
    unsigned u7 = Xt[(unsigned)(p7 & 0xffff) * 64 + lane];

__global__ __launch_bounds__(256)
void k_aggw(const unsigned* __restrict__ Xt, unsigned* __restrict__ AW,
            const int* __restrict__ off, const int* __restrict__ esrcF) {
    const int wid = threadIdx.x >> 6, lane = threadIdx.x & 63;
    const int v = blockIdx.x * 4 + wid;
    if (v >= NN) return;
    const int s = off[v], e = off[v + 1];
    float l0 = 0, l1 = 0, l2 = 0, l3 = 0, l4 = 0, l5 = 0, l6 = 0, l7 = 0;
    float h0 = 0, h1 = 0, h2 = 0, h3 = 0, h4 = 0, h5 = 0, h6 = 0, h7 = 0;
#define ACCW(P, U)                                                       \
    do {                                                                 \
        float _lo = bflo(U), _hi = bfhi(U);                              \
        switch ((P) >> 16) {                                             \
            case 0: l0 += _lo; h0 += _hi; break;                         \
            case 1: l1 += _lo; h1 += _hi; break;                         \
            case 2: l2 += _lo; h2 += _hi; break;                         \
            case 3: l3 += _lo; h3 += _hi; break;                         \
            case 4: l4 += _lo; h4 += _hi; break;                         \
            case 5: l5 += _lo; h5 += _hi; break;                         \
            case 6: l6 += _lo; h6 += _hi; break;                         \
            default: l7 += _lo; h7 += _hi; break;                        \
        }                                                                \
    } while (0)
    for (int j = s; j < e; j += 8) {
        LOAD8
        ACCW(p0, u0);
        if (j + 1 < e) ACCW(p1, u1);
        if (j + 2 < e) ACCW(p2, u2);
        if (j + 3 < e) ACCW(p3, u3);
        if (j + 4 < e) ACCW(p4, u4);
        if (j + 5 < e) ACCW(p5, u5);
        if (j + 6 < e) ACCW(p6, u6);
        if (j + 7 < e) ACCW(p7, u7);
    }
#undef ACCW
    unsigned* o = AW + (size_t)v * 512 + lane;
    o[0]   = pack2(l0, h0);
    o[64]  = pack2(l1, h1);
    o[128] = pack2(l2, h2);
    o[192] = pack2(l3, h3);
    o[256] = pack2(l4, h4);
    o[320] = pack2(l5, h5);
    o[384] = pack2(l6, h6);
    o[448] = pack2(l7, h7);
}

__global__ __launch_bounds__(256)
void k_aggh(const unsigned* __restrict__ Xt, unsigned* __restrict__ AH,
            const int* __restrict__ off, const int* __restrict__ esrcF,
            const float* __restrict__ invdeg) {
    const int wid = threadIdx.x >> 6, lane = threadIdx.x & 63;
    const int v = blockIdx.x * 4 + wid;
    if (v >= NN) return;
    const int s = off[v], e = off[v + 1];
    float a0 = 0.f, a1 = 0.f;
    for (int j = s; j < e; j += 8) {
        LOAD8
        (void)p0;
        a0 += bflo(u0); a1 += bfhi(u0);
        if (j + 1 < e) { a0 += bflo(u1); a1 += bfhi(u1); }
        if (j + 2 < e) { a0 += bflo(u2); a1 += bfhi(u2); }
        if (j + 3 < e) { a0 += bflo(u3); a1 += bfhi(u3); }
        if (j + 4 < e) { a0 += bflo(u4); a1 += bfhi(u4); }
        if (j + 5 < e) { a0 += bflo(u5); a1 += bfhi(u5); }
        if (j + 6 < e) { a0 += bflo(u6); a1 += bfhi(u6); }
        if (j + 7 < e) { a0 += bflo(u7); a1 += bfhi(u7); }
    }
    float inv = invdeg[v];
    AH[(size_t)v * 64 + lane] = pack2(a0 * inv, a1 * inv);
}

// ---------------- bf16 MFMA GEMM: LDS-staged B (swizzled), chunked K ----------------
// Y[M,N] = A[M,K] @ B[K,N]; Wc = chunk-blocked swizzled weights [NCHUNK][N][128]
// A chunk 0 from A0 (stride 128); chunks 1.. from A1 (stride 1024, offset (kc-1)*128)
// MODE 0: v=relu(acc*invdeg[row]); Yf=v; Ybf=bf(v)
// MODE 1: v=aux + alpha*(acc+bias); Ybf=bf(v)
// MODE 2: Yf=acc+bias
template <int N, int MODE, int NCHUNK>
__global__ __launch_bounds__(256)
void k_mfma(const short* __restrict__ A0, const short* __restrict__ A1,
            const short* __restrict__ Wc,
            float* __restrict__ Yf, unsigned short* __restrict__ Ybf,
            const float* __restrict__ aux, const float* __restrict__ bias,
            const float* __restrict__ alpha_p, const float* __restrict__ invdeg) {
    constexpr int NT = N / 16;
    constexpr int NIT = N / 16;          // staging iters: N*256 B / (4 waves * 1024 B)
    __shared__ short Bs[N * 128];
    const int tid = threadIdx.x;
    const int wave = tid >> 6;
    const int lane = tid & 63;
    const int lr = lane & 15;
    const int lk = (lane >> 4) * 8;
    const int rowBase = blockIdx.x * 64 + wave * 16;
    const int r0 = min(rowBase + lr, NN - 1);

    f32x4 acc[NT];
    #pragma unroll
    for (int nt = 0; nt < NT; ++nt) acc[nt] = f32x4{0.f, 0.f, 0.f, 0.f};

    for (int kc = 0; kc < NCHUNK; ++kc) {
        // stage B chunk (linear LDS write; source pre-inverse-swizzled)
        {
            const char* gs = (const char*)Wc + (size_t)kc * N * 256
                             + (wave * NIT) * 1024 + lane * 16;
            char* ls = (char*)Bs + (wave * NIT) * 1024;
            #pragma unroll
            for (int j = 0; j < NIT; ++j)
                gl2lds16(gs + j * 1024, ls + j * 1024);
        }
        // A fragments for this chunk (issued before barrier; drained by it)
        const short* abase = (kc == 0) ? (A0 + (size_t)r0 * 128)
                                       : (A1 + (size_t)r0 * 1024 + (kc - 1) * 128);
        bf16x8 a0 = *reinterpret_cast<const bf16x8*>(abase + 0 + lk);
        bf16x8 a1 = *reinterpret_cast<const bf16x8*>(abase + 32 + lk);
        bf16x8 a2 = *reinterpret_cast<const bf16x8*>(abase + 64 + lk);
        bf16x8 a3 = *reinterpret_cast<const bf16x8*>(abase + 96 + lk);
        __syncthreads();   // Bs ready (compiler drains vmcnt before s_barrier)

        #pragma unroll
        for (int s = 0; s < 4; ++s) {
            bf16x8 a = (s == 0) ? a0 : (s == 1) ? a1 : (s == 2) ? a2 : a3;
            #pragma unroll
            for (int nt = 0; nt < NT; ++nt) {
                const int c = nt * 16 + lr;
                const int e0 = (s * 32 + lk) ^ ((c & 7) << 3);   // swizzled read
                bf16x8 b = *reinterpret_cast<const bf16x8*>(
                    (const char*)Bs + c * 256 + e0 * 2);
                acc[nt] = __builtin_amdgcn_mfma_f32_16x16x32_bf16(a, b, acc[nt], 0, 0, 0);
            }
        }
        __syncthreads();   // protect Bs from next chunk's staging
    }

    const float al = (MODE == 1) ? *alpha_p : 0.f;
    #pragma unroll
    for (int j = 0; j < 4; ++j) {
        const int row = rowBase + (lane >> 4) * 4 + j;
        if (row >= NN) continue;
        float idg = (MODE == 0) ? invdeg[row] : 0.f;
        #pragma unroll
        for (int nt = 0; nt < NT; ++nt) {
            const int col = nt * 16 + lr;
            float v = acc[nt][j];
            if (MODE == 0) {
                v = fmaxf(v * idg, 0.f);
                Yf[(size_t)row * 128 + col] = v;
                Ybf[(size_t)row * 128 + col] = (unsigned short)f2bf_rne(v);
            } else if (MODE == 1) {
                v = aux[(size_t)row * 128 + col] + al * (v + bias[col]);
                Ybf[(size_t)row * 128 + col] = (unsigned short)f2bf_rne(v);
            } else {
                Yf[(size_t)row * 64 + col] = v + bias[col];
            }
        }
    }
}

// ---------------- launch ----------------

extern "C" void kernel_launch(void* const* d_in, const int* in_sizes, int n_in,
                              void* d_out, int out_size, void* d_ws, size_t ws_size,
                              hipStream_t stream) {
    const float* X   = (const float*)d_in[0];
    const int*   ei  = (const int*)d_in[1];
    const int*   et  = (const int*)d_in[2];
    const float* W1  = (const float*)d_in[3];
    const float* W01 = (const float*)d_in[4];
    const float* al1 = (const float*)d_in[5];
    const float* p1w = (const float*)d_in[6];
    const float* p1b = (const float*)d_in[7];
    const float* W2  = (const float*)d_in[8];
    const float* W02 = (const float*)d_in[9];
    const float* al2 = (const float*)d_in[10];
    const float* p2w = (const float*)d_in[11];
    const float* p2b = (const float*)d_in[12];
    const float* ow  = (const float*)d_in[13];
    const float* ob  = (const float*)d_in[14];
    float* out = (float*)d_out;

    char* wsp = (char*)d_ws;
    size_t o = 0;
    auto take = [&](size_t bytes) -> void* {
        void* p = wsp + o;
        o = (o + bytes + 255) & ~(size_t)255;
        return p;
    };
    int*      cntmat = (int*)take((size_t)NCB * NBLK * 4);
    int*      colsum = (int*)take((size_t)NCB * 4);
    int*      bstart = (int*)take((size_t)(NCB + 1) * 4);
    int*      off    = (int*)take((size_t)(NN + 1) * 4);
    float*    invdeg = (float*)take((size_t)NN * 4);
    int*      bck    = (int*)take((size_t)NE * 4);
    int*      esrcF  = (int*)take((size_t)(NE + 8) * 4);     // +8 overread slack
    unsigned* T1     = (unsigned*)take((size_t)NN * 64 * 4); // Xbf  -> H2bf
    unsigned* T2     = (unsigned*)take((size_t)NN * 64 * 4); // Hbf  -> G2bf
    unsigned* T3     = (unsigned*)take((size_t)NN * 64 * 4); // G1bf
    unsigned* AW     = (unsigned*)take((size_t)NN * 512 * 4);
    unsigned* AH     = (unsigned*)take((size_t)NN * 64 * 4);
    float*    Hf     = (float*)take((size_t)NN * 128 * 4);
    unsigned short* WtC1 = (unsigned short*)take((size_t)128 * 1152 * 2);
    unsigned short* WtC2 = (unsigned short*)take((size_t)128 * 1152 * 2);
    unsigned short* Wtp1 = (unsigned short*)take((size_t)128 * 128 * 2);
    unsigned short* Wtp2 = (unsigned short*)take((size_t)128 * 128 * 2);
    unsigned short* WtO  = (unsigned short*)take((size_t)64 * 128 * 2);
    if (o > ws_size) return;

    // ---- CSR build (atomic-free radix partition; dst-keyed, rel in payload) ----
    k_cnt<<<NBLK, 1024, 0, stream>>>(ei, cntmat);
    k_colscan<<<NCB, 64, 0, stream>>>(cntmat, colsum);
    k_bscan<<<1, 1024, 0, stream>>>(colsum, bstart, off);
    k_pscatter<<<NBLK, 1024, 0, stream>>>(ei, et, cntmat, bstart, bck);
    k_build<<<NCB, 256, 0, stream>>>(bck, bstart, off, invdeg, esrcF);

    // ---- prep ----
    k_prep_x<<<(NN * 64 + 255) / 256, 256, 0, stream>>>(X, T1);
    k_prep_wcat<<<(128 * 1152 + 255) / 256, 256, 0, stream>>>(W01, W1, WtC1);
    k_prep_wcat<<<(128 * 1152 + 255) / 256, 256, 0, stream>>>(W02, W2, WtC2);
    k_prep_wt<<<(128 * 128 + 255) / 256, 256, 0, stream>>>(p1w, Wtp1, 128);
    k_prep_wt<<<(128 * 128 + 255) / 256, 256, 0, stream>>>(p2w, Wtp2, 128);
    k_prep_wt<<<(64 * 128 + 255) / 256, 256, 0, stream>>>(ow, WtO, 64);

    const int GAGG = (NN + 3) / 4;   // 12500 blocks, wave per node

    // ---- layer 1 ----
    k_aggw<<<GAGG, 256, 0, stream>>>(T1, AW, off, esrcF);
    k_mfma<128, 0, 9><<<GRIDM, 256, 0, stream>>>(
        (const short*)T1, (const short*)AW, (const short*)WtC1,
        Hf, (unsigned short*)T2, nullptr, nullptr, nullptr, invdeg);
    k_aggh<<<GAGG, 256, 0, stream>>>(T2, AH, off, esrcF, invdeg);
    k_mfma<128, 1, 1><<<GRIDM, 256, 0, stream>>>(
        (const short*)AH, nullptr, (const short*)Wtp1,
        nullptr, (unsigned short*)T3, Hf, p1b, al1, nullptr);

    // ---- layer 2 ----
    k_aggw<<<GAGG, 256, 0, stream>>>(T3, AW, off, esrcF);
    k_mfma<128, 0, 9><<<GRIDM, 256, 0, stream>>>(
        (const short*)T3, (const short*)AW, (const short*)WtC2,
        Hf, (unsigned short*)T1, nullptr, nullptr, nullptr, invdeg);
    k_aggh<<<GAGG, 256, 0, stream>>>(T1, AH, off, esrcF, invdeg);
    k_mfma<128, 1, 1><<<GRIDM, 256, 0, stream>>>(
        (const short*)AH, nullptr, (const short*)Wtp2,
        nullptr, (unsigned short*)T2, Hf, p2b, al2, nullptr);

    // ---- final projection ----
    k_mfma<64, 2, 1><<<GRIDM, 256, 0, stream>>>(
        (const short*)T2, nullptr, (const short*)WtO,
        out, nullptr, nullptr, ob, nullptr, nullptr);
}

// Round 8
// 555.516 us; speedup vs baseline: 2.0994x; 1.0122x over previous
//
#include <hip/hip_runtime.h>
#include <hip/hip_bf16.h>

#define NN 50000
#define NE 1600000
#define NR 8
#define D 128
#define DOUT 64
#define NCB ((NN + 63) / 64)          // 782 coarse buckets (dst>>6)
#define NBLK 256                      // partition blocks
#define CH ((NE + NBLK - 1) / NBLK)   // 6250 edges per partition block
#define GRIDM ((NN + 63) / 64)        // 782 M-tiles for MFMA GEMM

typedef __attribute__((ext_vector_type(8))) __bf16 bf16x8;
typedef __attribute__((ext_vector_type(4))) float f32x4;

__device__ __forceinline__ float bflo(unsigned u) { return __uint_as_float(u << 16); }
__device__ __forceinline__ float bfhi(unsigned u) { return __uint_as_float(u & 0xffff0000u); }
__device__ __forceinline__ unsigned f2bf_rne(float x) {
    unsigned u = __float_as_uint(x);
    return (u + 0x7fffu + ((u >> 16) & 1u)) >> 16;
}
__device__ __forceinline__ unsigned pack2(float a, float b) {
    return f2bf_rne(a) | (f2bf_rne(b) << 16);
}

// async global->LDS, 16B per lane; LDS dest = wave-uniform base + lane*16
__device__ __forceinline__ void gl2lds16(const void* g, void* l) {
    __builtin_amdgcn_global_load_lds(
        (const __attribute__((address_space(1))) unsigned int*)g,
        (__attribute__((address_space(3))) unsigned int*)l, 16, 0, 0);
}

// ---------------- CSR build: atomic-free radix partition ----------------
__global__ __launch_bounds__(1024)
void k_cnt(const int* __restrict__ ei, int* __restrict__ cntmat) {
    __shared__ int h[NCB];
    const int blk = blockIdx.x, tid = threadIdx.x;
    for (int i = tid; i < NCB; i += 1024) h[i] = 0;
    __syncthreads();
    const int e0 = blk * CH, e1 = min(e0 + CH, NE);
    for (int e = e0 + tid; e < e1; e += 1024)
        atomicAdd(&h[ei[NE + e] >> 6], 1);
    __syncthreads();
    for (int i = tid; i < NCB; i += 1024) cntmat[i * NBLK + blk] = h[i];
}

__global__ __launch_bounds__(64)
void k_colscan(int* __restrict__ cntmat, int* __restrict__ colsum) {
    const int b = blockIdx.x, lane = threadIdx.x;
    int4 v = *reinterpret_cast<int4*>(cntmat + b * NBLK + lane * 4);
    int s = v.x + v.y + v.z + v.w;
    int e = s;
    #pragma unroll
    for (int o = 1; o < 64; o <<= 1) {
        int y = __shfl_up(e, o);
        if (lane >= o) e += y;
    }
    int excl = e - s;
    int4 w;
    w.x = excl; w.y = excl + v.x; w.z = excl + v.x + v.y; w.w = excl + v.x + v.y + v.z;
    *reinterpret_cast<int4*>(cntmat + b * NBLK + lane * 4) = w;
    if (lane == 63) colsum[b] = e;
}

__global__ __launch_bounds__(1024)
void k_bscan(const int* __restrict__ colsum, int* __restrict__ bstart) {
    __shared__ int s[1024];
    int t = threadIdx.x;
    int v = (t < NCB) ? colsum[t] : 0;
    s[t] = v;
    __syncthreads();
    for (int o = 1; o < 1024; o <<= 1) {
        int x = (t >= o) ? s[t - o] : 0;
        __syncthreads();
        s[t] += x;
        __syncthreads();
    }
    if (t < NCB) bstart[t] = s[t] - v;
    if (t == 0) bstart[NCB] = NE;
}

// pack: dstlo(6) << 19 | rel(3) << 16 | src(16)
__global__ __launch_bounds__(1024)
void k_pscatter(const int* __restrict__ ei, const int* __restrict__ et,
                const int* __restrict__ cntmat, const int* __restrict__ bstart,
                int* __restrict__ bck) {
    __shared__ int cur[NCB];
    const int blk = blockIdx.x, tid = threadIdx.x;
    for (int i = tid; i < NCB; i += 1024)
        cur[i] = bstart[i] + cntmat[i * NBLK + blk];
    __syncthreads();
    const int e0 = blk * CH, e1 = min(e0 + CH, NE);
    for (int e = e0 + tid; e < e1; e += 1024) {
        int dst = ei[NE + e];
        int pk = ((dst & 63) << 19) | (et[e] << 16) | ei[e];
        int p = atomicAdd(&cur[dst >> 6], 1);
        bck[p] = pk;
    }
}

// per coarse bucket: 512-bin (dstlo*8+rel) LDS hist/scan -> off8 CSR, rel-sorted scatter
__global__ __launch_bounds__(256)
void k_build(const int* __restrict__ bck, const int* __restrict__ cbase,
             int* __restrict__ off8, float* __restrict__ invdeg,
             int* __restrict__ esrcF) {
    __shared__ int cnt[512];
    __shared__ int cur[512];
    __shared__ int wtot[4];
    __shared__ int sb[2];
    const int b = blockIdx.x;
    const int tid = threadIdx.x;
    const int wid = tid >> 6, lane = tid & 63;
    cnt[tid] = 0; cnt[tid + 256] = 0;
    if (tid == 0) { sb[0] = cbase[b]; sb[1] = cbase[b + 1]; }
    __syncthreads();
    const int s0 = sb[0], s1 = sb[1];
    for (int i = s0 + tid; i < s1; i += 256)
        atomicAdd(&cnt[(bck[i] >> 16) & 511], 1);
    __syncthreads();
    // scan 512 bins with 256 threads (2 bins each), wave scan + cross-wave
    int c0 = cnt[2 * tid], c1 = cnt[2 * tid + 1];
    int ps = c0 + c1;
    int x = ps;
    #pragma unroll
    for (int o = 1; o < 64; o <<= 1) {
        int y = __shfl_up(x, o);
        if (lane >= o) x += y;
    }
    if (lane == 63) wtot[wid] = x;
    __syncthreads();
    int woff = 0;
    #pragma unroll
    for (int w2 = 0; w2 < 4; ++w2) woff += (w2 < wid) ? wtot[w2] : 0;
    int base = s0 + woff + x - ps;           // exclusive prefix of bin 2*tid
    cur[2 * tid] = base;
    cur[2 * tid + 1] = base + c0;
    off8[(size_t)b * 512 + 2 * tid] = base;
    off8[(size_t)b * 512 + 2 * tid + 1] = base + c0;
    if (tid < 64) {
        int gd = b * 64 + tid;
        if (gd < NN) {
            int dsum = 0;
            #pragma unroll
            for (int r = 0; r < 8; ++r) dsum += cnt[tid * 8 + r];
            invdeg[gd] = 1.0f / (float)max(dsum, 1);
        }
    }
    __syncthreads();
    for (int i = s0 + tid; i < s1; i += 256) {
        int pk = bck[i];
        int p = atomicAdd(&cur[(pk >> 16) & 511], 1);
        esrcF[p] = pk & 0xFFFF;   // src only (rel implied by position)
    }
}

// ---------------- prep: fp32 -> bf16 tables (weights: chunk-blocked + XOR-swizzled) --

__global__ void k_prep_x(const float* __restrict__ X, unsigned* __restrict__ Xt) {
    int i = blockIdx.x * blockDim.x + threadIdx.x;
    if (i < NN * 64) {
        float2 f = reinterpret_cast<const float2*>(X)[i];
        Xt[i] = pack2(f.x, f.y);
    }
}

// dst layout: [kc][n][e] where e = (k&127) ^ ((n&7)<<3)
__global__ void k_prep_wcat(const float* __restrict__ W0, const float* __restrict__ Wr,
                            unsigned short* __restrict__ dst) {
    int i = blockIdx.x * blockDim.x + threadIdx.x;
    if (i < 128 * 1152) {
        int n = i / 1152, k = i % 1152;
        float v = (k < 128) ? W0[k * 128 + n] : Wr[(k - 128) * 128 + n];
        int kc = k >> 7, kl = k & 127;
        int e = kl ^ ((n & 7) << 3);
        dst[((size_t)kc * 128 + n) * 128 + e] = (unsigned short)f2bf_rne(v);
    }
}

// src [128][N] f32 -> dst [N][128] bf16, swizzled: dst[n][k ^ ((n&7)<<3)]
__global__ void k_prep_wt(const float* __restrict__ src, unsigned short* __restrict__ dst,
                          int N) {
    int i = blockIdx.x * blockDim.x + threadIdx.x;
    if (i < N * 128) {
        int n = i >> 7, k = i & 127;
        int e = k ^ ((n & 7) << 3);
        dst[n * 128 + e] = (unsigned short)f2bf_rne(src[k * N + n]);
    }
}

// ---------------- aggregation: one wave per dst ----------------

// wide per-relation agg, rel-sorted subsegments, branchless accumulate
__global__ __launch_bounds__(256)
void k_aggw(const unsigned* __restrict__ Xt, unsigned* __restrict__ AW,
            const int* __restrict__ off8, const int* __restrict__ esrcF) {
    const int wid = threadIdx.x >> 6, lane = threadIdx.x & 63;
    const int v = blockIdx.x * 4 + wid;
    if (v >= NN) return;
    unsigned* o = AW + (size_t)v * 512 + lane;
    int s = off8[v * 8];
    for (int r = 0; r < 8; ++r) {
        const int e = off8[v * 8 + r + 1];
        float a0 = 0.f, a1 = 0.f;
        for (int j = s; j < e; j += 4) {
            int p0 = __builtin_amdgcn_readfirstlane(esrcF[j]);
            int p1 = __builtin_amdgcn_readfirstlane(esrcF[j + 1]);
            int p2 = __builtin_amdgcn_readfirstlane(esrcF[j + 2]);
            int p3 = __builtin_amdgcn_readfirstlane(esrcF[j + 3]);
            unsigned u0 = Xt[(unsigned)(p0 & 0xffff) * 64 + lane];
            unsigned u1 = Xt[(unsigned)(p1 & 0xffff) * 64 + lane];
            unsigned u2 = Xt[(unsigned)(p2 & 0xffff) * 64 + lane];
            unsigned u3 = Xt[(unsigned)(p3 & 0xffff) * 64 + lane];
            a0 += bflo(u0); a1 += bfhi(u0);
            if (j + 1 < e) { a0 += bflo(u1); a1 += bfhi(u1); }
            if (j + 2 < e) { a0 += bflo(u2); a1 += bfhi(u2); }
            if (j + 3 < e) { a0 += bflo(u3); a1 += bfhi(u3); }
        }
        o[r * 64] = pack2(a0, a1);
        s = e;
    }
}

// full-graph agg with invdeg scale
__global__ __launch_bounds__(256)
void k_aggh(const unsigned* __restrict__ Xt, unsigned* __restrict__ AH,
            const int* __restrict__ off8, const int* __restrict__ esrcF,
            const float* __restrict__ invdeg) {
    const int wid = threadIdx.x >> 6, lane = threadIdx.x & 63;
    const int v = blockIdx.x * 4 + wid;
    if (v >= NN) return;
    const int s = off8[v * 8], e = off8[v * 8 + 8];
    float a0 = 0.f, a1 = 0.f;
    for (int j = s; j < e; j += 8) {
        int p0 = __builtin_amdgcn_readfirstlane(esrcF[j]);
        int p1 = __builtin_amdgcn_readfirstlane(esrcF[j + 1]);
        int p2 = __builtin_amdgcn_readfirstlane(esrcF[j + 2]);
        int p3 = __builtin_amdgcn_readfirstlane(esrcF[j + 3]);
        int p4 = __builtin_amdgcn_readfirstlane(esrcF[j + 4]);
        int p5 = __builtin_amdgcn_readfirstlane(esrcF[j + 5]);
        int p6 = __builtin_amdgcn_readfirstlane(esrcF[j + 6]);
        int p7 = __builtin_amdgcn_readfirstlane(esrcF[j + 7]);
        unsigned u0 = Xt[(unsigned)(p0 & 0xffff) * 64 + lane];
        unsigned u1 = Xt[(unsigned)(p1 & 0xffff) * 64 + lane];
        unsigned u2 = Xt[(unsigned)(p2 & 0xffff) * 64 + lane];
        unsigned u3 = Xt[(unsigned)(p3 & 0xffff) * 64 + lane];
        unsigned u4 = Xt[(unsigned)(p4 & 0xffff) * 64 + lane];
        unsigned u5 = Xt[(unsigned)(p5 & 0xffff) * 64 + lane];
        unsigned u6 = Xt[(unsigned)(p6 & 0xffff) * 64 + lane];
        unsigned u7 = Xt[(unsigned)(p7 & 0xffff) * 64 + lane];
        a0 += bflo(u0); a1 += bfhi(u0);
        if (j + 1 < e) { a0 += bflo(u1); a1 += bfhi(u1); }
        if (j + 2 < e) { a0 += bflo(u2); a1 += bfhi(u2); }
        if (j + 3 < e) { a0 += bflo(u3); a1 += bfhi(u3); }
        if (j + 4 < e) { a0 += bflo(u4); a1 += bfhi(u4); }
        if (j + 5 < e) { a0 += bflo(u5); a1 += bfhi(u5); }
        if (j + 6 < e) { a0 += bflo(u6); a1 += bfhi(u6); }
        if (j + 7 < e) { a0 += bflo(u7); a1 += bfhi(u7); }
    }
    float inv = invdeg[v];
    AH[(size_t)v * 64 + lane] = pack2(a0 * inv, a1 * inv);
}

// ---------------- bf16 MFMA GEMM: LDS-staged B (swizzled), chunked K ----------------
template <int N, int MODE, int NCHUNK>
__global__ __launch_bounds__(256)
void k_mfma(const short* __restrict__ A0, const short* __restrict__ A1,
            const short* __restrict__ Wc,
            float* __restrict__ Yf, unsigned short* __restrict__ Ybf,
            const float* __restrict__ aux, const float* __restrict__ bias,
            const float* __restrict__ alpha_p, const float* __restrict__ invdeg) {
    constexpr int NT = N / 16;
    constexpr int NIT = N / 16;          // staging iters
    __shared__ short Bs[N * 128];
    const int tid = threadIdx.x;
    const int wave = tid >> 6;
    const int lane = tid & 63;
    const int lr = lane & 15;
    const int lk = (lane >> 4) * 8;
    const int rowBase = blockIdx.x * 64 + wave * 16;
    const int r0 = min(rowBase + lr, NN - 1);

    f32x4 acc[NT];
    #pragma unroll
    for (int nt = 0; nt < NT; ++nt) acc[nt] = f32x4{0.f, 0.f, 0.f, 0.f};

    for (int kc = 0; kc < NCHUNK; ++kc) {
        {
            const char* gs = (const char*)Wc + (size_t)kc * N * 256
                             + (wave * NIT) * 1024 + lane * 16;
            char* ls = (char*)Bs + (wave * NIT) * 1024;
            #pragma unroll
            for (int j = 0; j < NIT; ++j)
                gl2lds16(gs + j * 1024, ls + j * 1024);
        }
        const short* abase = (kc == 0) ? (A0 + (size_t)r0 * 128)
                                       : (A1 + (size_t)r0 * 1024 + (kc - 1) * 128);
        bf16x8 a0 = *reinterpret_cast<const bf16x8*>(abase + 0 + lk);
        bf16x8 a1 = *reinterpret_cast<const bf16x8*>(abase + 32 + lk);
        bf16x8 a2 = *reinterpret_cast<const bf16x8*>(abase + 64 + lk);
        bf16x8 a3 = *reinterpret_cast<const bf16x8*>(abase + 96 + lk);
        __syncthreads();

        #pragma unroll
        for (int s = 0; s < 4; ++s) {
            bf16x8 a = (s == 0) ? a0 : (s == 1) ? a1 : (s == 2) ? a2 : a3;
            #pragma unroll
            for (int nt = 0; nt < NT; ++nt) {
                const int c = nt * 16 + lr;
                const int e0 = (s * 32 + lk) ^ ((c & 7) << 3);
                bf16x8 b = *reinterpret_cast<const bf16x8*>(
                    (const char*)Bs + c * 256 + e0 * 2);
                acc[nt] = __builtin_amdgcn_mfma_f32_16x16x32_bf16(a, b, acc[nt], 0, 0, 0);
            }
        }
        __syncthreads();
    }

    const float al = (MODE == 1) ? *alpha_p : 0.f;
    #pragma unroll
    for (int j = 0; j < 4; ++j) {
        const int row = rowBase + (lane >> 4) * 4 + j;
        if (row >= NN) continue;
        float idg = (MODE == 0) ? invdeg[row] : 0.f;
        #pragma unroll
        for (int nt = 0; nt < NT; ++nt) {
            const int col = nt * 16 + lr;
            float v = acc[nt][j];
            if (MODE == 0) {
                v = fmaxf(v * idg, 0.f);
                Yf[(size_t)row * 128 + col] = v;
                Ybf[(size_t)row * 128 + col] = (unsigned short)f2bf_rne(v);
            } else if (MODE == 1) {
                v = aux[(size_t)row * 128 + col] + al * (v + bias[col]);
                Ybf[(size_t)row * 128 + col] = (unsigned short)f2bf_rne(v);
            } else {
                Yf[(size_t)row * 64 + col] = v + bias[col];
            }
        }
    }
}

// ---------------- launch ----------------

extern "C" void kernel_launch(void* const* d_in, const int* in_sizes, int n_in,
                              void* d_out, int out_size, void* d_ws, size_t ws_size,
                              hipStream_t stream) {
    const float* X   = (const float*)d_in[0];
    const int*   ei  = (const int*)d_in[1];
    const int*   et  = (const int*)d_in[2];
    const float* W1  = (const float*)d_in[3];
    const float* W01 = (const float*)d_in[4];
    const float* al1 = (const float*)d_in[5];
    const float* p1w = (const float*)d_in[6];
    const float* p1b = (const float*)d_in[7];
    const float* W2  = (const float*)d_in[8];
    const float* W02 = (const float*)d_in[9];
    const float* al2 = (const float*)d_in[10];
    const float* p2w = (const float*)d_in[11];
    const float* p2b = (const float*)d_in[12];
    const float* ow  = (const float*)d_in[13];
    const float* ob  = (const float*)d_in[14];
    float* out = (float*)d_out;

    char* wsp = (char*)d_ws;
    size_t o = 0;
    auto take = [&](size_t bytes) -> void* {
        void* p = wsp + o;
        o = (o + bytes + 255) & ~(size_t)255;
        return p;
    };
    int*      cntmat = (int*)take((size_t)NCB * NBLK * 4);
    int*      colsum = (int*)take((size_t)NCB * 4);
    int*      bstart = (int*)take((size_t)(NCB + 1) * 4);
    int*      off8   = (int*)take((size_t)(NCB * 512 + 1) * 4);  // fine CSR (dst,rel)
    float*    invdeg = (float*)take((size_t)NN * 4);
    int*      bck    = (int*)take((size_t)NE * 4);
    int*      esrcF  = (int*)take((size_t)(NE + 8) * 4);     // +8 overread slack
    unsigned* T1     = (unsigned*)take((size_t)NN * 64 * 4); // Xbf  -> H2bf
    unsigned* T2     = (unsigned*)take((size_t)NN * 64 * 4); // Hbf  -> G2bf
    unsigned* T3     = (unsigned*)take((size_t)NN * 64 * 4); // G1bf
    unsigned* AW     = (unsigned*)take((size_t)NN * 512 * 4);
    unsigned* AH     = (unsigned*)take((size_t)NN * 64 * 4);
    float*    Hf     = (float*)take((size_t)NN * 128 * 4);
    unsigned short* WtC1 = (unsigned short*)take((size_t)128 * 1152 * 2);
    unsigned short* WtC2 = (unsigned short*)take((size_t)128 * 1152 * 2);
    unsigned short* Wtp1 = (unsigned short*)take((size_t)128 * 128 * 2);
    unsigned short* Wtp2 = (unsigned short*)take((size_t)128 * 128 * 2);
    unsigned short* WtO  = (unsigned short*)take((size_t)64 * 128 * 2);
    if (o > ws_size) return;

    // ---- CSR build (atomic-free radix partition; rel-sorted fine CSR) ----
    k_cnt<<<NBLK, 1024, 0, stream>>>(ei, cntmat);
    k_colscan<<<NCB, 64, 0, stream>>>(cntmat, colsum);
    k_bscan<<<1, 1024, 0, stream>>>(colsum, bstart);
    k_pscatter<<<NBLK, 1024, 0, stream>>>(ei, et, cntmat, bstart, bck);
    k_build<<<NCB, 256, 0, stream>>>(bck, bstart, off8, invdeg, esrcF);

    // ---- prep ----
    k_prep_x<<<(NN * 64 + 255) / 256, 256, 0, stream>>>(X, T1);
    k_prep_wcat<<<(128 * 1152 + 255) / 256, 256, 0, stream>>>(W01, W1, WtC1);
    k_prep_wcat<<<(128 * 1152 + 255) / 256, 256, 0, stream>>>(W02, W2, WtC2);
    k_prep_wt<<<(128 * 128 + 255) / 256, 256, 0, stream>>>(p1w, Wtp1, 128);
    k_prep_wt<<<(128 * 128 + 255) / 256, 256, 0, stream>>>(p2w, Wtp2, 128);
    k_prep_wt<<<(64 * 128 + 255) / 256, 256, 0, stream>>>(ow, WtO, 64);

    const int GAGG = (NN + 3) / 4;   // 12500 blocks, wave per node

    // ---- layer 1 ----
    k_aggw<<<GAGG, 256, 0, stream>>>(T1, AW, off8, esrcF);
    k_mfma<128, 0, 9><<<GRIDM, 256, 0, stream>>>(
        (const short*)T1, (const short*)AW, (const short*)WtC1,
        Hf, (unsigned short*)T2, nullptr, nullptr, nullptr, invdeg);
    k_aggh<<<GAGG, 256, 0, stream>>>(T2, AH, off8, esrcF, invdeg);
    k_mfma<128, 1, 1><<<GRIDM, 256, 0, stream>>>(
        (const short*)AH, nullptr, (const short*)Wtp1,
        nullptr, (unsigned short*)T3, Hf, p1b, al1, nullptr);

    // ---- layer 2 ----
    k_aggw<<<GAGG, 256, 0, stream>>>(T3, AW, off8, esrcF);
    k_mfma<128, 0, 9><<<GRIDM, 256, 0, stream>>>(
        (const short*)T3, (const short*)AW, (const short*)WtC2,
        Hf, (unsigned short*)T1, nullptr, nullptr, nullptr, invdeg);
    k_aggh<<<GAGG, 256, 0, stream>>>(T1, AH, off8, esrcF, invdeg);
    k_mfma<128, 1, 1><<<GRIDM, 256, 0, stream>>>(
        (const short*)AH, nullptr, (const short*)Wtp2,
        nullptr, (unsigned short*)T2, Hf, p2b, al2, nullptr);

    // ---- final projection ----
    k_mfma<64, 2, 1><<<GRIDM, 256, 0, stream>>>(
        (const short*)T2, nullptr, (const short*)WtO,
        out, nullptr, nullptr, ob, nullptr, nullptr);
}